// Round 12
// baseline (199.744 us; speedup 1.0000x reference)
//
#include <hip/hip_runtime.h>
#include <hip/hip_fp16.h>
#include <math.h>

// ---------------------------------------------------------------------------
// VariationalGCNEncoder: N=50000, E=800000, 128 -> 64 -> {32,32}
// R12: R11 bucketed-counting-sort CSR + two refinements:
//  (1) gathers: ALL streaming traffic non-temporal (edges nt-load, outputs
//      nt-store) so the 6.4MB hp working set keeps max L2 residency.
//  (2) [gemm | hist] fused (hist is atomic-latency bound, 1.5% VALU — gemm
//      hides inside); dinv-prescale of hp moved into phaseB (each bucket
//      block scales its own 32KB hp slice, coalesced, LDS-cached dinv).
// Pipeline (7 nodes):
//   memset(bcount) -> [gemm(unscaled) | hist] -> bscan -> scatterA
//   -> phaseB (row_ptr, dinv, edge scatter, hp *= dinv)
//   -> gather1 (hm = dinv*relu(dinv*(sum hp[src]+hp[n])+b1), bf16, nt-out)
//   -> gather2 (out = dinv*(sum hm[src]+hm[n]) @ [Wmu|Wls] + bias, nt-out)
// ---------------------------------------------------------------------------

typedef unsigned int uint;
typedef unsigned short ushort;
typedef __attribute__((ext_vector_type(8))) short short8;   // 8 bf16 = 4 VGPR
typedef __attribute__((ext_vector_type(4))) float f32x4;    // MFMA acc
typedef __attribute__((ext_vector_type(2))) float f32v2;    // pk pair

__device__ __forceinline__ ushort f2bf(float x) {          // f32 -> bf16 RNE
    uint u = __float_as_uint(x);
    u += 0x7fffu + ((u >> 16) & 1u);
    return (ushort)(u >> 16);
}
__device__ __forceinline__ float bf2f(ushort h) {
    return __uint_as_float((uint)h << 16);
}

// blocks [0,GB): MFMA gemm hp = bf16(x)@bf16(W1) (UNscaled);
// blocks [GB,..): coarse histogram over dst>>8 (2048 edges/block).
__global__ __launch_bounds__(256, 4) void k_gemm_hist(
        const float* __restrict__ x, const float* __restrict__ W1,
        ushort* __restrict__ hp, int N, int GB,
        const int* __restrict__ dst, int* __restrict__ bcount, int E) {
    const int tid = threadIdx.x;
    if (blockIdx.x >= GB) {                        // ---- histogram ----
        __shared__ int h[256];
        h[tid] = 0;
        __syncthreads();
        const int base = (blockIdx.x - GB) * 2048;
        #pragma unroll
        for (int k = 0; k < 8; ++k) {
            int i = base + k * 256 + tid;
            if (i < E) {
                int d = __builtin_nontemporal_load(dst + i);
                atomicAdd(&h[d >> 8], 1);
            }
        }
        __syncthreads();
        if (h[tid]) atomicAdd(&bcount[tid], h[tid]);
        return;
    }
    // ---- MFMA gemm: wave = 16 rows x 64 cols, k=128 in 4 chunks ----
    const int w = tid >> 6, l = tid & 63;
    const int m = l & 15, q = l >> 4;              // q = quad (0..3)
    const int row0 = blockIdx.x * 64 + w * 16;
    const size_t arow = (size_t)min(row0 + m, N - 1);   // clamp; store guarded
    f32x4 acc0 = {0.f, 0.f, 0.f, 0.f}, acc1 = acc0, acc2 = acc0, acc3 = acc0;
    #pragma unroll
    for (int kc = 0; kc < 4; ++kc) {
        const int kofs = kc * 32 + q * 8;
        const float4* xr = (const float4*)(x + arow * 128 + kofs);
        float4 xa = xr[0], xb = xr[1];
        short8 a;
        a[0] = (short)f2bf(xa.x); a[1] = (short)f2bf(xa.y);
        a[2] = (short)f2bf(xa.z); a[3] = (short)f2bf(xa.w);
        a[4] = (short)f2bf(xb.x); a[5] = (short)f2bf(xb.y);
        a[6] = (short)f2bf(xb.z); a[7] = (short)f2bf(xb.w);
        short8 b0, b1, b2, b3;                     // W1 L1-hot (32 KB)
        #pragma unroll
        for (int i = 0; i < 8; ++i) {
            const float* wk = W1 + (size_t)(kofs + i) * 64 + m;
            b0[i] = (short)f2bf(wk[0]);
            b1[i] = (short)f2bf(wk[16]);
            b2[i] = (short)f2bf(wk[32]);
            b3[i] = (short)f2bf(wk[48]);
        }
        acc0 = __builtin_amdgcn_mfma_f32_16x16x32_bf16(a, b0, acc0, 0, 0, 0);
        acc1 = __builtin_amdgcn_mfma_f32_16x16x32_bf16(a, b1, acc1, 0, 0, 0);
        acc2 = __builtin_amdgcn_mfma_f32_16x16x32_bf16(a, b2, acc2, 0, 0, 0);
        acc3 = __builtin_amdgcn_mfma_f32_16x16x32_bf16(a, b3, acc3, 0, 0, 0);
    }
    #pragma unroll
    for (int r = 0; r < 4; ++r) {                  // D: row=q*4+r, col=g*16+m
        int row = row0 + q * 4 + r;
        if (row >= N) continue;
        ushort* hr = hp + (size_t)row * 64 + m;
        hr[0]  = f2bf(acc0[r]);
        hr[16] = f2bf(acc1[r]);
        hr[32] = f2bf(acc2[r]);
        hr[48] = f2bf(acc3[r]);
    }
}

// ---- bucket scan: bbase (excl prefix, bbase[256]=E), bcursor=bbase ----
__global__ __launch_bounds__(256) void k_bscan(
        const int* __restrict__ bcount, int* __restrict__ bbase,
        int* __restrict__ bcursor, int E) {
    __shared__ int p[256];
    const int t = threadIdx.x;
    int v = bcount[t];
    p[t] = v;
    __syncthreads();
    #pragma unroll
    for (int off = 1; off < 256; off <<= 1) {
        int x = (t >= off) ? p[t - off] : 0;
        __syncthreads();
        p[t] += x;
        __syncthreads();
    }
    int excl = p[t] - v;
    bbase[t] = excl;
    bcursor[t] = excl;
    if (t == 255) bbase[256] = p[255];   // == E
}

// ---- level A scatter: rec = src(16) | dstlow(8)<<16 | bucket(8)<<24 ----
__global__ __launch_bounds__(256) void k_scatterA(
        const int* __restrict__ src, const int* __restrict__ dst,
        int* __restrict__ bcursor, uint* __restrict__ recs, int E) {
    __shared__ int h[256];
    __shared__ int rb[256];
    const int tid = threadIdx.x;
    h[tid] = 0;
    __syncthreads();
    const int base = blockIdx.x * 2048;
    uint rec[8]; int rk[8];
    #pragma unroll
    for (int k = 0; k < 8; ++k) {
        int i = base + k * 256 + tid;
        if (i < E) {
            int s = __builtin_nontemporal_load(src + i);
            int d = __builtin_nontemporal_load(dst + i);
            int b = d >> 8;
            rec[k] = (uint)s | ((uint)(d & 255) << 16) | ((uint)b << 24);
            rk[k] = atomicAdd(&h[b], 1);
        }
    }
    __syncthreads();
    rb[tid] = h[tid] ? atomicAdd(&bcursor[tid], h[tid]) : 0;
    __syncthreads();
    #pragma unroll
    for (int k = 0; k < 8; ++k) {
        int i = base + k * 256 + tid;
        if (i < E) recs[rb[rec[k] >> 24] + rk[k]] = rec[k];
    }
}

// ---- level B: one block per bucket (256 nodes, ~4K edges). Produces
// row_ptr + dinv coalesced, scatters final u16 edges inside the block-local
// 8KB region, then scales its own hp slice by dinv (coalesced, LDS dinv).
__global__ __launch_bounds__(256) void k_phaseB(
        const uint* __restrict__ recs, const int* __restrict__ bbase,
        int* __restrict__ row_ptr, float* __restrict__ dinv,
        ushort* __restrict__ edges, uint* __restrict__ hp,
        int N, int E, int NBUCK) {
    __shared__ int h[256];
    __shared__ int p[256];
    __shared__ float sdv[256];
    const int tid = threadIdx.x;
    const int b = blockIdx.x;
    const int base = bbase[b];
    const int cnt  = bbase[b + 1] - base;
    h[tid] = 0;
    __syncthreads();
    for (int i = tid; i < cnt; i += 256)
        atomicAdd(&h[(recs[base + i] >> 16) & 255], 1);
    __syncthreads();
    int v = h[tid];
    p[tid] = v;
    __syncthreads();
    #pragma unroll
    for (int off = 1; off < 256; off <<= 1) {
        int x = (tid >= off) ? p[tid - off] : 0;
        __syncthreads();
        p[tid] += x;
        __syncthreads();
    }
    const int excl = p[tid] - v;
    const float dv = rsqrtf((float)(v + 1));
    sdv[tid] = dv;
    const int node = b * 256 + tid;
    if (node < N) {
        row_ptr[node] = base + excl;
        dinv[node] = dv;
    }
    if (b == NBUCK - 1 && tid == 0) row_ptr[N] = E;
    h[tid] = excl;                     // reuse as local cursor
    __syncthreads();
    for (int i = tid; i < cnt; i += 256) {
        uint r = recs[base + i];
        int dl = (r >> 16) & 255;
        int pos = atomicAdd(&h[dl], 1);
        edges[base + pos] = (ushort)(r & 0xffffu);
    }
    // ---- hp[rows of this bucket] *= dinv (coalesced, 32 uints/row) ----
    const int rows = min(256, N - b * 256);
    if (rows <= 0) return;
    uint* hpb = hp + (size_t)b * 256 * 32;
    for (int idx = tid; idx < rows * 32; idx += 256) {
        float d2 = sdv[idx >> 5];
        uint w = hpb[idx];
        float lo = bf2f((ushort)w) * d2;
        float hi = bf2f((ushort)(w >> 16)) * d2;
        hpb[idx] = (uint)f2bf(lo) | ((uint)f2bf(hi) << 16);
    }
}

// Norm-free gather over 64-feature rows (32 uints). Half-wave per edge:
// hl = lane&31 (feature pair), half = lane>>5 (edge parity). 2 edges/step,
// 8-step unroll = 16 row-loads in flight. Edge metadata nt-loaded (streamed
// once; keep L2 for hp). Butterfly at end.
__device__ __forceinline__ f32v2 gather_rows(
        const uint* __restrict__ hp, const ushort* __restrict__ edges,
        int beg, int end, int E, int lane, int hl, int half) {
    f32v2 acc = {0.f, 0.f};
    for (int base = beg; base < end; base += 64) {
        int cnt = end - base; if (cnt > 64) cnt = 64;
        int mrec = (int)__builtin_nontemporal_load(edges + min(base + lane, E - 1));
        int steps = (cnt + 1) >> 1;
        for (int t = 0; t < steps; t += 8) {
            if (2 * t + 16 <= cnt) {       // edges 2t..2t+15 all valid
                #pragma unroll
                for (int i = 0; i < 8; ++i) {
                    int r = __shfl(mrec, 2 * (t + i) + half);
                    uint v = hp[(size_t)r * 32 + hl];
                    f32v2 vf;
                    vf.x = __uint_as_float(v << 16);
                    vf.y = __uint_as_float(v & 0xffff0000u);
                    acc = acc + vf;
                }
            } else {
                #pragma unroll
                for (int i = 0; i < 8; ++i) {
                    int e = 2 * (t + i) + half;
                    int r = __shfl(mrec, min(e, cnt - 1));
                    uint v = hp[(size_t)r * 32 + hl];
                    v = (e < cnt) ? v : 0u;
                    f32v2 vf;
                    vf.x = __uint_as_float(v << 16);
                    vf.y = __uint_as_float(v & 0xffff0000u);
                    acc = acc + vf;
                }
            }
        }
    }
    acc.x += __shfl_xor(acc.x, 32);
    acc.y += __shfl_xor(acc.y, 32);
    return acc;
}

// hm[n] = dinv * relu( dinv * (sum hp[src] + hp[n]) + b1 )   (bf16x2, nt-out)
__global__ __launch_bounds__(256, 8) void k_gather1(
        const uint* __restrict__ hp, const int* __restrict__ row_ptr,
        const ushort* __restrict__ edges, const float* __restrict__ dinv,
        const float* __restrict__ b1, uint* __restrict__ ho, int N, int E) {
    const int lane = threadIdx.x & 63;
    const int hl = lane & 31, half = lane >> 5;
    const int n = blockIdx.x * 4 + (threadIdx.x >> 6);
    if (n >= N) return;
    const int beg = row_ptr[n], end = row_ptr[n + 1];
    f32v2 acc = gather_rows(hp, edges, beg, end, E, lane, hl, half);
    if (half == 0) {
        const float dv = dinv[n];
        const uint sv = hp[(size_t)n * 32 + hl];       // self (pre-scaled)
        const float2 b = ((const float2*)b1)[hl];
        float s0 = acc.x + bf2f((ushort)sv);
        float s1 = acc.y + bf2f((ushort)(sv >> 16));
        float h0 = fmaxf(fmaf(dv, s0, b.x), 0.f) * dv; // relu then pre-scale
        float h1 = fmaxf(fmaf(dv, s1, b.y), 0.f) * dv;
        uint pk = (uint)f2bf(h0) | ((uint)f2bf(h1) << 16);
        __builtin_nontemporal_store(pk, ho + (size_t)n * 32 + hl);
    }
}

// g = dinv*(sum hm[src] + hm[n]);  out[n] = g @ [Wmu|Wls] + bias  (nt-out)
__global__ __launch_bounds__(256, 8) void k_gather2(
        const uint* __restrict__ hp, const int* __restrict__ row_ptr,
        const ushort* __restrict__ edges, const float* __restrict__ dinv,
        const float* __restrict__ Wmu, const float* __restrict__ Wls,
        const float* __restrict__ bmu, const float* __restrict__ bls,
        float* __restrict__ out, int N, int E) {
    __shared__ float hs[4][64];    // per-wave g row (1 KB)
    const int lane = threadIdx.x & 63;
    const int hl = lane & 31, half = lane >> 5;
    const int w = threadIdx.x >> 6;
    const int n = blockIdx.x * 4 + w;
    if (n >= N) return;
    const int beg = row_ptr[n], end = row_ptr[n + 1];
    f32v2 acc = gather_rows(hp, edges, beg, end, E, lane, hl, half);
    if (half == 0) {
        const float dv = dinv[n];
        const uint sv = hp[(size_t)n * 32 + hl];
        float g0 = dv * (acc.x + bf2f((ushort)sv));
        float g1 = dv * (acc.y + bf2f((ushort)(sv >> 16)));
        float2 p; p.x = g0; p.y = g1;
        *(float2*)&hs[w][2 * hl] = p;
    }
    // epilogue: out_row = g @ [Wmu|Wls] + bias ; W from global (L1-hot)
    const float* Wsel = (lane < 32) ? (Wmu + lane) : (Wls + (lane - 32));
    const float bias  = (lane < 32) ? bmu[lane] : bls[lane - 32];
    float c0 = 0.f, c1 = 0.f, c2 = 0.f, c3 = 0.f;
    #pragma unroll 4
    for (int k = 0; k < 64; k += 4) {
        c0 = fmaf(hs[w][k + 0], Wsel[(k + 0) * 32], c0);
        c1 = fmaf(hs[w][k + 1], Wsel[(k + 1) * 32], c1);
        c2 = fmaf(hs[w][k + 2], Wsel[(k + 2) * 32], c2);
        c3 = fmaf(hs[w][k + 3], Wsel[(k + 3) * 32], c3);
    }
    float t = (c0 + c1) + (c2 + c3) + bias;
    if (lane < 32) __builtin_nontemporal_store(t, out + (size_t)n * 32 + lane);
    else __builtin_nontemporal_store(t, out + (size_t)N * 32 + (size_t)n * 32 + (lane - 32));
}

extern "C" void kernel_launch(void* const* d_in, const int* in_sizes, int n_in,
                              void* d_out, int out_size, void* d_ws, size_t ws_size,
                              hipStream_t stream) {
    const float* x   = (const float*)d_in[0];
    const int*   ei  = (const int*)d_in[1];
    const float* W1  = (const float*)d_in[2];
    const float* b1  = (const float*)d_in[3];
    const float* Wmu = (const float*)d_in[4];
    const float* bmu = (const float*)d_in[5];
    const float* Wls = (const float*)d_in[6];
    const float* bls = (const float*)d_in[7];
    float* out = (float*)d_out;

    const int N = in_sizes[0] / 128;          // 50000  (< 65536: u16 src pack)
    const int E = in_sizes[1] / 2;            // 800000
    const int* src = ei;
    const int* dst = ei + E;
    const int HB    = (E + 2047) / 2048;      // hist/scatterA blocks (391)
    const int NBUCK = (N + 255) / 256;        // coarse buckets (196)
    const int GB    = (N + 63) / 64;          // gemm row-tile blocks
    const int NG    = (N + 3) / 4;            // gather blocks

    char* w = (char*)d_ws;
    auto carve = [&](size_t bytes) { char* p = w; w += (bytes + 1023) & ~(size_t)1023; return p; };
    int*    bcount  = (int*)   carve(256 * 4);
    int*    bbase   = (int*)   carve(257 * 4);
    int*    bcursor = (int*)   carve(256 * 4);
    uint*   recs    = (uint*)  carve((size_t)E * 4);        // level-A records
    int*    row_ptr = (int*)   carve((size_t)(N + 1) * 4);
    float*  dinv    = (float*) carve((size_t)N * 4);
    ushort* edges   = (ushort*)carve((size_t)E * 2);        // u16 src records
    ushort* h_pre   = (ushort*)carve((size_t)NBUCK * 256 * 64 * 2);  // bf16, bucket-padded
    ushort* h_mid   = (ushort*)carve((size_t)N * 64 * 2);   // bf16 (pre-scaled)

    hipMemsetAsync(bcount, 0, 256 * 4, stream);
    k_gemm_hist<<<GB + HB, 256, 0, stream>>>(x, W1, h_pre, N, GB, dst, bcount, E);
    k_bscan    <<<1, 256, 0, stream>>>(bcount, bbase, bcursor, E);
    k_scatterA <<<HB, 256, 0, stream>>>(src, dst, bcursor, recs, E);
    k_phaseB   <<<NBUCK, 256, 0, stream>>>(recs, bbase, row_ptr, dinv, edges,
                                           (uint*)h_pre, N, E, NBUCK);
    k_gather1  <<<NG, 256, 0, stream>>>((const uint*)h_pre, row_ptr, edges, dinv,
                                        b1, (uint*)h_mid, N, E);
    k_gather2  <<<NG, 256, 0, stream>>>((const uint*)h_mid, row_ptr, edges, dinv,
                                        Wmu, Wls, bmu, bls, out, N, E);
}

// Round 13
// 197.976 us; speedup vs baseline: 1.0089x; 1.0089x over previous
//
#include <hip/hip_runtime.h>
#include <hip/hip_fp16.h>
#include <math.h>

// ---------------------------------------------------------------------------
// VariationalGCNEncoder: N=50000, E=800000, 128 -> 64 -> {32,32}
// R13: R12 minus its mistake. (1) h_mid store is CACHED again (it is
//      gather2's random working set — R12's nt-store kept it out of L2 and
//      cold-started gather2). (2) gather metadata preload clamped to the
//      node's edge range (was fetching 64 records/node for ~16 used: 8x
//      metadata over-fetch). Rest identical to R12 (R11 CSR build,
//      [gemm|hist] fused, phaseB dinv-prescale, nt edges/out).
// Pipeline (7 nodes):
//   memset(bcount) -> [gemm(unscaled) | hist] -> bscan -> scatterA
//   -> phaseB (row_ptr, dinv, edge scatter, hp *= dinv)
//   -> gather1 (hm = dinv*relu(dinv*(sum hp[src]+hp[n])+b1), bf16)
//   -> gather2 (out = dinv*(sum hm[src]+hm[n]) @ [Wmu|Wls] + bias, nt-out)
// ---------------------------------------------------------------------------

typedef unsigned int uint;
typedef unsigned short ushort;
typedef __attribute__((ext_vector_type(8))) short short8;   // 8 bf16 = 4 VGPR
typedef __attribute__((ext_vector_type(4))) float f32x4;    // MFMA acc
typedef __attribute__((ext_vector_type(2))) float f32v2;    // pk pair

__device__ __forceinline__ ushort f2bf(float x) {          // f32 -> bf16 RNE
    uint u = __float_as_uint(x);
    u += 0x7fffu + ((u >> 16) & 1u);
    return (ushort)(u >> 16);
}
__device__ __forceinline__ float bf2f(ushort h) {
    return __uint_as_float((uint)h << 16);
}

// blocks [0,GB): MFMA gemm hp = bf16(x)@bf16(W1) (UNscaled);
// blocks [GB,..): coarse histogram over dst>>8 (2048 edges/block).
__global__ __launch_bounds__(256, 4) void k_gemm_hist(
        const float* __restrict__ x, const float* __restrict__ W1,
        ushort* __restrict__ hp, int N, int GB,
        const int* __restrict__ dst, int* __restrict__ bcount, int E) {
    const int tid = threadIdx.x;
    if (blockIdx.x >= GB) {                        // ---- histogram ----
        __shared__ int h[256];
        h[tid] = 0;
        __syncthreads();
        const int base = (blockIdx.x - GB) * 2048;
        #pragma unroll
        for (int k = 0; k < 8; ++k) {
            int i = base + k * 256 + tid;
            if (i < E) {
                int d = __builtin_nontemporal_load(dst + i);
                atomicAdd(&h[d >> 8], 1);
            }
        }
        __syncthreads();
        if (h[tid]) atomicAdd(&bcount[tid], h[tid]);
        return;
    }
    // ---- MFMA gemm: wave = 16 rows x 64 cols, k=128 in 4 chunks ----
    const int w = tid >> 6, l = tid & 63;
    const int m = l & 15, q = l >> 4;              // q = quad (0..3)
    const int row0 = blockIdx.x * 64 + w * 16;
    const size_t arow = (size_t)min(row0 + m, N - 1);   // clamp; store guarded
    f32x4 acc0 = {0.f, 0.f, 0.f, 0.f}, acc1 = acc0, acc2 = acc0, acc3 = acc0;
    #pragma unroll
    for (int kc = 0; kc < 4; ++kc) {
        const int kofs = kc * 32 + q * 8;
        const float4* xr = (const float4*)(x + arow * 128 + kofs);
        float4 xa = xr[0], xb = xr[1];
        short8 a;
        a[0] = (short)f2bf(xa.x); a[1] = (short)f2bf(xa.y);
        a[2] = (short)f2bf(xa.z); a[3] = (short)f2bf(xa.w);
        a[4] = (short)f2bf(xb.x); a[5] = (short)f2bf(xb.y);
        a[6] = (short)f2bf(xb.z); a[7] = (short)f2bf(xb.w);
        short8 b0, b1, b2, b3;                     // W1 L1-hot (32 KB)
        #pragma unroll
        for (int i = 0; i < 8; ++i) {
            const float* wk = W1 + (size_t)(kofs + i) * 64 + m;
            b0[i] = (short)f2bf(wk[0]);
            b1[i] = (short)f2bf(wk[16]);
            b2[i] = (short)f2bf(wk[32]);
            b3[i] = (short)f2bf(wk[48]);
        }
        acc0 = __builtin_amdgcn_mfma_f32_16x16x32_bf16(a, b0, acc0, 0, 0, 0);
        acc1 = __builtin_amdgcn_mfma_f32_16x16x32_bf16(a, b1, acc1, 0, 0, 0);
        acc2 = __builtin_amdgcn_mfma_f32_16x16x32_bf16(a, b2, acc2, 0, 0, 0);
        acc3 = __builtin_amdgcn_mfma_f32_16x16x32_bf16(a, b3, acc3, 0, 0, 0);
    }
    #pragma unroll
    for (int r = 0; r < 4; ++r) {                  // D: row=q*4+r, col=g*16+m
        int row = row0 + q * 4 + r;
        if (row >= N) continue;
        ushort* hr = hp + (size_t)row * 64 + m;
        hr[0]  = f2bf(acc0[r]);
        hr[16] = f2bf(acc1[r]);
        hr[32] = f2bf(acc2[r]);
        hr[48] = f2bf(acc3[r]);
    }
}

// ---- bucket scan: bbase (excl prefix, bbase[256]=E), bcursor=bbase ----
__global__ __launch_bounds__(256) void k_bscan(
        const int* __restrict__ bcount, int* __restrict__ bbase,
        int* __restrict__ bcursor, int E) {
    __shared__ int p[256];
    const int t = threadIdx.x;
    int v = bcount[t];
    p[t] = v;
    __syncthreads();
    #pragma unroll
    for (int off = 1; off < 256; off <<= 1) {
        int x = (t >= off) ? p[t - off] : 0;
        __syncthreads();
        p[t] += x;
        __syncthreads();
    }
    int excl = p[t] - v;
    bbase[t] = excl;
    bcursor[t] = excl;
    if (t == 255) bbase[256] = p[255];   // == E
}

// ---- level A scatter: rec = src(16) | dstlow(8)<<16 | bucket(8)<<24 ----
__global__ __launch_bounds__(256) void k_scatterA(
        const int* __restrict__ src, const int* __restrict__ dst,
        int* __restrict__ bcursor, uint* __restrict__ recs, int E) {
    __shared__ int h[256];
    __shared__ int rb[256];
    const int tid = threadIdx.x;
    h[tid] = 0;
    __syncthreads();
    const int base = blockIdx.x * 2048;
    uint rec[8]; int rk[8];
    #pragma unroll
    for (int k = 0; k < 8; ++k) {
        int i = base + k * 256 + tid;
        if (i < E) {
            int s = __builtin_nontemporal_load(src + i);
            int d = __builtin_nontemporal_load(dst + i);
            int b = d >> 8;
            rec[k] = (uint)s | ((uint)(d & 255) << 16) | ((uint)b << 24);
            rk[k] = atomicAdd(&h[b], 1);
        }
    }
    __syncthreads();
    rb[tid] = h[tid] ? atomicAdd(&bcursor[tid], h[tid]) : 0;
    __syncthreads();
    #pragma unroll
    for (int k = 0; k < 8; ++k) {
        int i = base + k * 256 + tid;
        if (i < E) recs[rb[rec[k] >> 24] + rk[k]] = rec[k];
    }
}

// ---- level B: one block per bucket (256 nodes, ~4K edges). Produces
// row_ptr + dinv coalesced, scatters final u16 edges inside the block-local
// 8KB region, then scales its own hp slice by dinv (coalesced, LDS dinv).
__global__ __launch_bounds__(256) void k_phaseB(
        const uint* __restrict__ recs, const int* __restrict__ bbase,
        int* __restrict__ row_ptr, float* __restrict__ dinv,
        ushort* __restrict__ edges, uint* __restrict__ hp,
        int N, int E, int NBUCK) {
    __shared__ int h[256];
    __shared__ int p[256];
    __shared__ float sdv[256];
    const int tid = threadIdx.x;
    const int b = blockIdx.x;
    const int base = bbase[b];
    const int cnt  = bbase[b + 1] - base;
    h[tid] = 0;
    __syncthreads();
    for (int i = tid; i < cnt; i += 256)
        atomicAdd(&h[(recs[base + i] >> 16) & 255], 1);
    __syncthreads();
    int v = h[tid];
    p[tid] = v;
    __syncthreads();
    #pragma unroll
    for (int off = 1; off < 256; off <<= 1) {
        int x = (tid >= off) ? p[tid - off] : 0;
        __syncthreads();
        p[tid] += x;
        __syncthreads();
    }
    const int excl = p[tid] - v;
    const float dv = rsqrtf((float)(v + 1));
    sdv[tid] = dv;
    const int node = b * 256 + tid;
    if (node < N) {
        row_ptr[node] = base + excl;
        dinv[node] = dv;
    }
    if (b == NBUCK - 1 && tid == 0) row_ptr[N] = E;
    h[tid] = excl;                     // reuse as local cursor
    __syncthreads();
    for (int i = tid; i < cnt; i += 256) {
        uint r = recs[base + i];
        int dl = (r >> 16) & 255;
        int pos = atomicAdd(&h[dl], 1);
        edges[base + pos] = (ushort)(r & 0xffffu);
    }
    // ---- hp[rows of this bucket] *= dinv (coalesced, 32 uints/row) ----
    const int rows = min(256, N - b * 256);
    if (rows <= 0) return;
    uint* hpb = hp + (size_t)b * 256 * 32;
    for (int idx = tid; idx < rows * 32; idx += 256) {
        float d2 = sdv[idx >> 5];
        uint w = hpb[idx];
        float lo = bf2f((ushort)w) * d2;
        float hi = bf2f((ushort)(w >> 16)) * d2;
        hpb[idx] = (uint)f2bf(lo) | ((uint)f2bf(hi) << 16);
    }
}

// Norm-free gather over 64-feature rows (32 uints). Half-wave per edge:
// hl = lane&31 (feature pair), half = lane>>5 (edge parity). 2 edges/step,
// 8-step unroll = 16 row-loads in flight. Metadata preload CLAMPED to the
// node's range (1 line/node typ., was 4). Edge metadata nt-loaded.
__device__ __forceinline__ f32v2 gather_rows(
        const uint* __restrict__ hp, const ushort* __restrict__ edges,
        int beg, int end, int E, int lane, int hl, int half) {
    f32v2 acc = {0.f, 0.f};
    for (int base = beg; base < end; base += 64) {
        int cnt = end - base; if (cnt > 64) cnt = 64;
        int mrec = (int)__builtin_nontemporal_load(edges + base + min(lane, cnt - 1));
        int steps = (cnt + 1) >> 1;
        for (int t = 0; t < steps; t += 8) {
            if (2 * t + 16 <= cnt) {       // edges 2t..2t+15 all valid
                #pragma unroll
                for (int i = 0; i < 8; ++i) {
                    int r = __shfl(mrec, 2 * (t + i) + half);
                    uint v = hp[(size_t)r * 32 + hl];
                    f32v2 vf;
                    vf.x = __uint_as_float(v << 16);
                    vf.y = __uint_as_float(v & 0xffff0000u);
                    acc = acc + vf;
                }
            } else {
                #pragma unroll
                for (int i = 0; i < 8; ++i) {
                    int e = 2 * (t + i) + half;
                    int r = __shfl(mrec, min(e, cnt - 1));
                    uint v = hp[(size_t)r * 32 + hl];
                    v = (e < cnt) ? v : 0u;
                    f32v2 vf;
                    vf.x = __uint_as_float(v << 16);
                    vf.y = __uint_as_float(v & 0xffff0000u);
                    acc = acc + vf;
                }
            }
        }
    }
    acc.x += __shfl_xor(acc.x, 32);
    acc.y += __shfl_xor(acc.y, 32);
    return acc;
}

// hm[n] = dinv * relu( dinv * (sum hp[src] + hp[n]) + b1 )   (bf16x2)
// NOTE: hm stored CACHED — it is gather2's random working set.
__global__ __launch_bounds__(256, 8) void k_gather1(
        const uint* __restrict__ hp, const int* __restrict__ row_ptr,
        const ushort* __restrict__ edges, const float* __restrict__ dinv,
        const float* __restrict__ b1, uint* __restrict__ ho, int N, int E) {
    const int lane = threadIdx.x & 63;
    const int hl = lane & 31, half = lane >> 5;
    const int n = blockIdx.x * 4 + (threadIdx.x >> 6);
    if (n >= N) return;
    const int beg = row_ptr[n], end = row_ptr[n + 1];
    f32v2 acc = gather_rows(hp, edges, beg, end, E, lane, hl, half);
    if (half == 0) {
        const float dv = dinv[n];
        const uint sv = hp[(size_t)n * 32 + hl];       // self (pre-scaled)
        const float2 b = ((const float2*)b1)[hl];
        float s0 = acc.x + bf2f((ushort)sv);
        float s1 = acc.y + bf2f((ushort)(sv >> 16));
        float h0 = fmaxf(fmaf(dv, s0, b.x), 0.f) * dv; // relu then pre-scale
        float h1 = fmaxf(fmaf(dv, s1, b.y), 0.f) * dv;
        ho[(size_t)n * 32 + hl] = (uint)f2bf(h0) | ((uint)f2bf(h1) << 16);
    }
}

// g = dinv*(sum hm[src] + hm[n]);  out[n] = g @ [Wmu|Wls] + bias  (nt-out)
__global__ __launch_bounds__(256, 8) void k_gather2(
        const uint* __restrict__ hp, const int* __restrict__ row_ptr,
        const ushort* __restrict__ edges, const float* __restrict__ dinv,
        const float* __restrict__ Wmu, const float* __restrict__ Wls,
        const float* __restrict__ bmu, const float* __restrict__ bls,
        float* __restrict__ out, int N, int E) {
    __shared__ float hs[4][64];    // per-wave g row (1 KB)
    const int lane = threadIdx.x & 63;
    const int hl = lane & 31, half = lane >> 5;
    const int w = threadIdx.x >> 6;
    const int n = blockIdx.x * 4 + w;
    if (n >= N) return;
    const int beg = row_ptr[n], end = row_ptr[n + 1];
    f32v2 acc = gather_rows(hp, edges, beg, end, E, lane, hl, half);
    if (half == 0) {
        const float dv = dinv[n];
        const uint sv = hp[(size_t)n * 32 + hl];
        float g0 = dv * (acc.x + bf2f((ushort)sv));
        float g1 = dv * (acc.y + bf2f((ushort)(sv >> 16)));
        float2 p; p.x = g0; p.y = g1;
        *(float2*)&hs[w][2 * hl] = p;
    }
    // epilogue: out_row = g @ [Wmu|Wls] + bias ; W from global (L1-hot)
    const float* Wsel = (lane < 32) ? (Wmu + lane) : (Wls + (lane - 32));
    const float bias  = (lane < 32) ? bmu[lane] : bls[lane - 32];
    float c0 = 0.f, c1 = 0.f, c2 = 0.f, c3 = 0.f;
    #pragma unroll 4
    for (int k = 0; k < 64; k += 4) {
        c0 = fmaf(hs[w][k + 0], Wsel[(k + 0) * 32], c0);
        c1 = fmaf(hs[w][k + 1], Wsel[(k + 1) * 32], c1);
        c2 = fmaf(hs[w][k + 2], Wsel[(k + 2) * 32], c2);
        c3 = fmaf(hs[w][k + 3], Wsel[(k + 3) * 32], c3);
    }
    float t = (c0 + c1) + (c2 + c3) + bias;
    if (lane < 32) __builtin_nontemporal_store(t, out + (size_t)n * 32 + lane);
    else __builtin_nontemporal_store(t, out + (size_t)N * 32 + (size_t)n * 32 + (lane - 32));
}

extern "C" void kernel_launch(void* const* d_in, const int* in_sizes, int n_in,
                              void* d_out, int out_size, void* d_ws, size_t ws_size,
                              hipStream_t stream) {
    const float* x   = (const float*)d_in[0];
    const int*   ei  = (const int*)d_in[1];
    const float* W1  = (const float*)d_in[2];
    const float* b1  = (const float*)d_in[3];
    const float* Wmu = (const float*)d_in[4];
    const float* bmu = (const float*)d_in[5];
    const float* Wls = (const float*)d_in[6];
    const float* bls = (const float*)d_in[7];
    float* out = (float*)d_out;

    const int N = in_sizes[0] / 128;          // 50000  (< 65536: u16 src pack)
    const int E = in_sizes[1] / 2;            // 800000
    const int* src = ei;
    const int* dst = ei + E;
    const int HB    = (E + 2047) / 2048;      // hist/scatterA blocks (391)
    const int NBUCK = (N + 255) / 256;        // coarse buckets (196)
    const int GB    = (N + 63) / 64;          // gemm row-tile blocks
    const int NG    = (N + 3) / 4;            // gather blocks

    char* w = (char*)d_ws;
    auto carve = [&](size_t bytes) { char* p = w; w += (bytes + 1023) & ~(size_t)1023; return p; };
    int*    bcount  = (int*)   carve(256 * 4);
    int*    bbase   = (int*)   carve(257 * 4);
    int*    bcursor = (int*)   carve(256 * 4);
    uint*   recs    = (uint*)  carve((size_t)E * 4);        // level-A records
    int*    row_ptr = (int*)   carve((size_t)(N + 1) * 4);
    float*  dinv    = (float*) carve((size_t)N * 4);
    ushort* edges   = (ushort*)carve((size_t)E * 2);        // u16 src records
    ushort* h_pre   = (ushort*)carve((size_t)NBUCK * 256 * 64 * 2);  // bf16, bucket-padded
    ushort* h_mid   = (ushort*)carve((size_t)N * 64 * 2);   // bf16 (pre-scaled)

    hipMemsetAsync(bcount, 0, 256 * 4, stream);
    k_gemm_hist<<<GB + HB, 256, 0, stream>>>(x, W1, h_pre, N, GB, dst, bcount, E);
    k_bscan    <<<1, 256, 0, stream>>>(bcount, bbase, bcursor, E);
    k_scatterA <<<HB, 256, 0, stream>>>(src, dst, bcursor, recs, E);
    k_phaseB   <<<NBUCK, 256, 0, stream>>>(recs, bbase, row_ptr, dinv, edges,
                                           (uint*)h_pre, N, E, NBUCK);
    k_gather1  <<<NG, 256, 0, stream>>>((const uint*)h_pre, row_ptr, edges, dinv,
                                        b1, (uint*)h_mid, N, E);
    k_gather2  <<<NG, 256, 0, stream>>>((const uint*)h_mid, row_ptr, edges, dinv,
                                        Wmu, Wls, bmu, bls, out, N, E);
}